// Round 7
// baseline (663.209 us; speedup 1.0000x reference)
//
#include <hip/hip_runtime.h>
#include <stdint.h>

// Problem constants (fixed by reference setup_inputs)
#define B_ROWS 4096
#define D_DIM  512
#define K_CODES 16384
#define EPS 1e-6f

typedef __attribute__((ext_vector_type(8))) short short8;   // 8 bf16 (raw bits)
typedef __attribute__((ext_vector_type(4))) float floatx4;  // MFMA accumulator

__device__ __forceinline__ unsigned short f2bf(float f) {
  // round-to-nearest-even fp32 -> bf16 (inputs finite, no NaN handling)
  unsigned int u = __float_as_uint(f);
  u += 0x7FFFu + ((u >> 16) & 1u);
  return (unsigned short)(u >> 16);
}
__device__ __forceinline__ float bf2f(unsigned short h) {
  return __uint_as_float(((unsigned int)h) << 16);
}

__device__ __forceinline__ void load_lds16(const short* g, short* l) {
  // async global->LDS, 16B/lane; LDS dest = wave-uniform base + lane*16
  __builtin_amdgcn_global_load_lds(
      (const __attribute__((address_space(1))) void*)g,
      (__attribute__((address_space(3))) void*)l, 16, 0, 0);
}

// ---------------------------------------------------------------------------
// prep (single launch):
//  blocks 0..1023  : w-path. 64(d)x128(k) tile: 512B-contiguous row reads
//                    (R5's 64x64 tiles only achieved 256B segments), LDS
//                    transpose (stride 129: transpose reads are 2-way = free),
//                    short8 (16B) hi/lo stores, per-(d-chunk,k) colpart.
//  blocks 1024..1279: x path. x (4096x512) -> A_cat (4096x1024 [x_hi|x_lo]) +
//                    row_term[b]. One wave per row, 16 rows/block.
//                    Block 1024 zero-inits loss_acc/counter2/cnt[32].
// ---------------------------------------------------------------------------
__global__ void prep_kernel(const float* __restrict__ x,
                            const float* __restrict__ w,
                            short* __restrict__ A, short* __restrict__ W,
                            float* __restrict__ row_term,
                            float* __restrict__ colpart,
                            float* __restrict__ loss_acc,
                            unsigned int* __restrict__ counter2,
                            unsigned int* __restrict__ cnt) {
  const int bid = blockIdx.x;
  const int t = threadIdx.x;  // 256
  if (bid < 1024) {
    __shared__ float tile[64][129];  // 33 KB
    const int k0 = (bid & 127) * 128;
    const int dchunk = bid >> 7;  // 0..7
    const int d0 = dchunk * 64;
#pragma unroll
    for (int i = 0; i < 8; ++i) {
      int idx = i * 256 + t;
      int r = idx >> 5, c = (idx & 31) * 4;  // r: d-local; 32 lanes = 512 B
      float4 v = *(const float4*)&w[(size_t)(d0 + r) * K_CODES + k0 + c];
      tile[r][c + 0] = v.x;
      tile[r][c + 1] = v.y;
      tile[r][c + 2] = v.z;
      tile[r][c + 3] = v.w;
    }
    __syncthreads();
    const int sub = t & 7;    // d-subgroup within a k row
    const int cd8 = sub * 8;  // 8 consecutive d
#pragma unroll
    for (int g = 0; g < 4; ++g) {
      const int rk = (t >> 3) + g * 32;  // k-local 0..127
      short8 hi, lo;
      float s = 0.f, q = 0.f;
#pragma unroll
      for (int j = 0; j < 8; ++j) {
        float v = tile[cd8 + j][rk];
        s += v;
        q += v * v;
        unsigned short h = f2bf(v);
        float r2 = v - bf2f(h);
        hi[j] = (short)h;
        lo[j] = (short)f2bf(r2);
      }
      *(short8*)(W + (size_t)(k0 + rk) * 1024 + d0 + cd8) = hi;
      *(short8*)(W + (size_t)(k0 + rk) * 1024 + 512 + d0 + cd8) = lo;
#pragma unroll
      for (int m = 1; m < 8; m <<= 1) {
        s += __shfl_xor(s, m, 64);
        q += __shfl_xor(q, m, 64);
      }
      if (sub == 0)
        colpart[(size_t)dchunk * K_CODES + k0 + rk] = q - 2.0f * EPS * s;
    }
  } else {
    const int xb = bid - 1024;  // 0..255
    if (xb == 0) {
      if (t == 0) { loss_acc[0] = 0.0f; counter2[0] = 0u; }
      if (t < 32) cnt[t] = 0u;
    }
    const int wv = t >> 6, lane = t & 63;
#pragma unroll
    for (int i = 0; i < 4; ++i) {
      const int b = xb * 16 + i * 4 + wv;  // one wave per row
      const float* xr = x + (size_t)b * D_DIM;
      float4 v0 = ((const float4*)xr)[lane * 2];
      float4 v1 = ((const float4*)xr)[lane * 2 + 1];
      float vals[8] = {v0.x, v0.y, v0.z, v0.w, v1.x, v1.y, v1.z, v1.w};
      short8 hi, lo;
      float s = 0.f, q = 0.f;
#pragma unroll
      for (int j = 0; j < 8; ++j) {
        float v = vals[j];
        s += v;
        q += v * v;
        unsigned short h = f2bf(v);
        float r = v - bf2f(h);
        hi[j] = (short)h;
        lo[j] = (short)f2bf(r);
      }
      *(short8*)(A + (size_t)b * 1024 + lane * 8) = hi;
      *(short8*)(A + (size_t)b * 1024 + 512 + lane * 8) = lo;
#pragma unroll
      for (int m = 1; m < 64; m <<= 1) {
        s += __shfl_xor(s, m, 64);
        q += __shfl_xor(q, m, 64);
      }
      if (lane == 0) row_term[b] = q + 2.0f * EPS * s + (float)D_DIM * EPS * EPS;
    }
  }
}

// ---------------------------------------------------------------------------
// som_gemm: R5 K-loop (proven 212us; R6's producer-consumer regressed to
// 414us — single producer wave exposes full vmem latency at every barrier
// because __syncthreads drains vmcnt(0); occupancy collapsed to 1 block/CU).
// 128x128 tile, BK=64, 4 waves of 64x64, XOR-swizzled LDS (conflicts = 0),
// __launch_bounds__(256,4) -> 64 VGPR + 64 AGPR = 4 blocks/CU.
// NEW (R7): finalize fused into the epilogue. Per-mt arrival counter: the
// 128th block for an mt scans partial[0..127][mt rows], computes BMU
// locations + sqrt + loss for its 128 rows; the 32nd mt-finalizer writes the
// mean loss. Fence discipline: every writer __threadfence() -> __syncthreads
// -> one device-scope atomic (release); finalizer re-fences (acquire).
// ---------------------------------------------------------------------------
__global__ __launch_bounds__(256, 4) void som_gemm_kernel(
    const short* __restrict__ A, const short* __restrict__ W,
    const float* __restrict__ row_term, const float* __restrict__ colpart,
    unsigned long long* __restrict__ partial,
    const float* __restrict__ loc, float* __restrict__ out,
    float* __restrict__ loss_acc, unsigned int* __restrict__ counter2,
    unsigned int* __restrict__ cnt) {
  __shared__ __align__(16) short As[128 * 64];
  __shared__ __align__(16) short Bs[128 * 64];
  __shared__ int flag_s;

  const int nt = blockIdx.x;  // 0..127
  const int mt = blockIdx.y;  // 0..31
  const int m0 = mt * 128, n0 = nt * 128;
  const int tid = threadIdx.x;
  const int wv = tid >> 6, lane = tid & 63;
  const int m_off = (wv & 1) * 64, n_off = (wv >> 1) * 64;
  const int q = lane >> 4, l15 = lane & 15;

  floatx4 acc[4][4];
  const floatx4 zero = {0.f, 0.f, 0.f, 0.f};
#pragma unroll
  for (int mi = 0; mi < 4; ++mi)
#pragma unroll
    for (int ni = 0; ni < 4; ++ni) acc[mi][ni] = zero;

  const int srow = lane >> 3;                      // row within 8-row chunk
  const int scol = ((lane & 7) ^ (srow & 7)) * 8;  // XOR-swizzled source col

  for (int kt = 0; kt < 24; ++kt) {
    // virtual k' in [0,1536): terms hi*hi (kt 0..7), lo*hi (8..15), hi*lo (16..23)
    const int a_k0 = (kt * 64) & 1023;
    const int w_k0 = (kt < 16) ? ((kt * 64) & 511) : (kt * 64 - 512);
    __syncthreads();  // previous iter's ds_reads done before overwrite
#pragma unroll
    for (int i = 0; i < 4; ++i) {
      const int c = wv * 4 + i;  // chunk 0..15, covers rows c*8..c*8+7
      const int row = c * 8 + srow;
      load_lds16(A + (size_t)(m0 + row) * 1024 + a_k0 + scol, As + c * 512);
      load_lds16(W + (size_t)(n0 + row) * 1024 + w_k0 + scol, Bs + c * 512);
    }
    __syncthreads();  // waits vmcnt(0): staging complete
#pragma unroll
    for (int ks = 0; ks < 2; ++ks) {
      const int sw = ((ks * 4 + q) ^ (l15 & 7)) * 8;
      short8 af[4], bf[4];
#pragma unroll
      for (int mi = 0; mi < 4; ++mi)
        af[mi] = *(const short8*)(As + (m_off + mi * 16 + l15) * 64 + sw);
#pragma unroll
      for (int ni = 0; ni < 4; ++ni)
        bf[ni] = *(const short8*)(Bs + (n_off + ni * 16 + l15) * 64 + sw);
#pragma unroll
      for (int mi = 0; mi < 4; ++mi)
#pragma unroll
        for (int ni = 0; ni < 4; ++ni)
          acc[mi][ni] = __builtin_amdgcn_mfma_f32_16x16x32_bf16(
              af[mi], bf[ni], acc[mi][ni], 0, 0, 0);
    }
  }

  // epilogue: ct[k] summed from the 8 d-chunk partials (L2-hot, deterministic)
  float ct[4];
#pragma unroll
  for (int ni = 0; ni < 4; ++ni) {
    const int k = n0 + n_off + ni * 16 + l15;
    float s = 0.f;
#pragma unroll
    for (int c = 0; c < 8; ++c) s += colpart[(size_t)c * K_CODES + k];
    ct[ni] = s;
  }
  float rt[16];
#pragma unroll
  for (int mi = 0; mi < 4; ++mi)
#pragma unroll
    for (int r = 0; r < 4; ++r)
      rt[mi * 4 + r] = row_term[m0 + m_off + mi * 16 + q * 4 + r];

  __syncthreads();  // all waves done reading As before lds_min aliases it
  unsigned long long* lds_min = (unsigned long long*)As;  // [2][128]

#pragma unroll
  for (int mi = 0; mi < 4; ++mi) {
#pragma unroll
    for (int r = 0; r < 4; ++r) {
      unsigned long long v = ~0ull;
#pragma unroll
      for (int ni = 0; ni < 4; ++ni) {
        float d2 = rt[mi * 4 + r] + ct[ni] - 2.0f * acc[mi][ni][r];
        d2 = fmaxf(d2, 0.0f);  // >=0 so float bit order == value order
        unsigned long long p =
            ((unsigned long long)__float_as_uint(d2) << 32) |
            (unsigned int)(n0 + n_off + ni * 16 + l15);
        v = p < v ? p : v;
      }
#pragma unroll
      for (int mms = 1; mms < 16; mms <<= 1) {
        unsigned long long o = __shfl_xor(v, mms, 64);
        v = o < v ? o : v;
      }
      if (l15 == 0) lds_min[(wv >> 1) * 128 + m_off + mi * 16 + q * 4 + r] = v;
    }
  }
  __syncthreads();
  if (tid < 128) {
    unsigned long long v0 = lds_min[tid];
    unsigned long long v1 = lds_min[128 + tid];
    partial[(size_t)nt * B_ROWS + m0 + tid] = v1 < v0 ? v1 : v0;
  }

  // ---- fused finalize: last-arriving block per mt reduces its 128 rows ----
  __threadfence();   // release this thread's partial stores (device scope)
  __syncthreads();
  if (tid == 0) {
    unsigned int old = atomicAdd(&cnt[mt], 1u);
    flag_s = (old == 127u) ? 1 : 0;
  }
  __syncthreads();
  if (flag_s) {
    __threadfence();  // acquire: see all blocks' partial stores
    const int row = tid & 127;   // row within mt
    const int half = tid >> 7;   // nt range half
    unsigned long long v = ~0ull;
#pragma unroll 8
    for (int i = 0; i < 64; ++i) {
      const int ntt = half * 64 + i;
      unsigned long long p = partial[(size_t)ntt * B_ROWS + m0 + row];
      v = p < v ? p : v;
    }
    unsigned long long* red = (unsigned long long*)As;  // lds_min consumed
    red[tid] = v;
    __syncthreads();
    float* wsum = (float*)Bs;  // Bs dead
    if (tid < 128) {
      unsigned long long a = red[tid], b = red[tid + 128];
      a = b < a ? b : a;
      unsigned int k = (unsigned int)(a & 0xFFFFFFFFu);
      float d2 = __uint_as_float((unsigned int)(a >> 32));
      float dist = sqrtf(d2);
      const int rg = m0 + tid;
      out[2 * rg] = loc[2 * k];
      out[2 * rg + 1] = loc[2 * k + 1];
      float s = dist;
#pragma unroll
      for (int m = 1; m < 64; m <<= 1) s += __shfl_xor(s, m, 64);
      if ((tid & 63) == 0) wsum[tid >> 6] = s;
    }
    __syncthreads();
    if (tid == 0) {
      atomicAdd(loss_acc, wsum[0] + wsum[1]);
      __threadfence();
      unsigned int o2 = atomicAdd(counter2, 1u);
      if (o2 == 31u) {
        __threadfence();
        float total = atomicAdd(loss_acc, 0.0f);  // coherent read-back
        out[2 * B_ROWS] = total * (1.0f / (float)B_ROWS);
      }
    }
  }
}

// ---------------------------------------------------------------------------
// Workspace layout (bytes):
//   A_cat    4096*1024*2  =  8,388,608   @ 0
//   W_cat   16384*1024*2  = 33,554,432   @ 8,388,608
//   row_term  4096*4      =     16,384   @ 41,943,040
//   colpart  8*16384*4    =    524,288   @ 41,959,424
//   partial 128*4096*8    =  4,194,304   @ 42,483,712
//   loss_acc 4                           @ 46,678,016
//   counter2 4                           @ 46,678,020
//   cnt[32]  128                         @ 46,678,024
// total ~46.7 MB
// ---------------------------------------------------------------------------
extern "C" void kernel_launch(void* const* d_in, const int* in_sizes, int n_in,
                              void* d_out, int out_size, void* d_ws, size_t ws_size,
                              hipStream_t stream) {
  const float* x = (const float*)d_in[0];
  const float* w = (const float*)d_in[1];
  const float* loc = (const float*)d_in[2];
  float* out = (float*)d_out;
  char* ws = (char*)d_ws;

  short* A = (short*)(ws + 0);
  short* W = (short*)(ws + 8388608);
  float* row_term = (float*)(ws + 41943040);
  float* colpart = (float*)(ws + 41959424);
  unsigned long long* partial = (unsigned long long*)(ws + 42483712);
  float* loss_acc = (float*)(ws + 46678016);
  unsigned int* counter2 = (unsigned int*)(ws + 46678020);
  unsigned int* cnt = (unsigned int*)(ws + 46678024);

  prep_kernel<<<1280, 256, 0, stream>>>(x, w, A, W, row_term, colpart,
                                        loss_acc, counter2, cnt);
  som_gemm_kernel<<<dim3(K_CODES / 128, B_ROWS / 128), 256, 0, stream>>>(
      A, W, row_term, colpart, partial, loc, out, loss_acc, counter2, cnt);
}

// Round 8
// 293.265 us; speedup vs baseline: 2.2615x; 2.2615x over previous
//
#include <hip/hip_runtime.h>
#include <stdint.h>

// Problem constants (fixed by reference setup_inputs)
#define B_ROWS 4096
#define D_DIM  512
#define K_CODES 16384
#define EPS 1e-6f

typedef __attribute__((ext_vector_type(8))) short short8;   // 8 bf16 (raw bits)
typedef __attribute__((ext_vector_type(4))) float floatx4;  // MFMA accumulator

__device__ __forceinline__ unsigned short f2bf(float f) {
  // round-to-nearest-even fp32 -> bf16 (inputs finite, no NaN handling)
  unsigned int u = __float_as_uint(f);
  u += 0x7FFFu + ((u >> 16) & 1u);
  return (unsigned short)(u >> 16);
}
__device__ __forceinline__ float bf2f(unsigned short h) {
  return __uint_as_float(((unsigned int)h) << 16);
}

__device__ __forceinline__ void load_lds16(const short* g, short* l) {
  // async global->LDS, 16B/lane; LDS dest = wave-uniform base + lane*16
  __builtin_amdgcn_global_load_lds(
      (const __attribute__((address_space(1))) void*)g,
      (__attribute__((address_space(3))) void*)l, 16, 0, 0);
}

// ---------------------------------------------------------------------------
// prep (single launch):
//  blocks 0..1023  : w-path. 64(d)x128(k) tile: 512B-contiguous row reads,
//                    LDS transpose (stride 129; transpose reads 2-way = free),
//                    short8 (16B) hi/lo stores, per-(d-chunk,k) colpart
//                    (summed by gemm epilogue; no atomics -> deterministic).
//  blocks 1024..1279: x path. x (4096x512) -> A_cat (4096x1024 [x_hi|x_lo]) +
//                    row_term[b]. One wave per row, 16 rows/block.
//                    Block 1024 zero-inits loss_acc/counter.
// ---------------------------------------------------------------------------
__global__ void prep_kernel(const float* __restrict__ x,
                            const float* __restrict__ w,
                            short* __restrict__ A, short* __restrict__ W,
                            float* __restrict__ row_term,
                            float* __restrict__ colpart,
                            float* __restrict__ loss_acc,
                            unsigned int* __restrict__ counter) {
  const int bid = blockIdx.x;
  const int t = threadIdx.x;  // 256
  if (bid < 1024) {
    __shared__ float tile[64][129];  // 33 KB
    const int k0 = (bid & 127) * 128;
    const int dchunk = bid >> 7;  // 0..7
    const int d0 = dchunk * 64;
#pragma unroll
    for (int i = 0; i < 8; ++i) {
      int idx = i * 256 + t;
      int r = idx >> 5, c = (idx & 31) * 4;  // r: d-local; 32 lanes = 512 B
      float4 v = *(const float4*)&w[(size_t)(d0 + r) * K_CODES + k0 + c];
      tile[r][c + 0] = v.x;
      tile[r][c + 1] = v.y;
      tile[r][c + 2] = v.z;
      tile[r][c + 3] = v.w;
    }
    __syncthreads();
    const int sub = t & 7;    // d-subgroup within a k row
    const int cd8 = sub * 8;  // 8 consecutive d
#pragma unroll
    for (int g = 0; g < 4; ++g) {
      const int rk = (t >> 3) + g * 32;  // k-local 0..127
      short8 hi, lo;
      float s = 0.f, q = 0.f;
#pragma unroll
      for (int j = 0; j < 8; ++j) {
        float v = tile[cd8 + j][rk];
        s += v;
        q += v * v;
        unsigned short h = f2bf(v);
        float r2 = v - bf2f(h);
        hi[j] = (short)h;
        lo[j] = (short)f2bf(r2);
      }
      *(short8*)(W + (size_t)(k0 + rk) * 1024 + d0 + cd8) = hi;
      *(short8*)(W + (size_t)(k0 + rk) * 1024 + 512 + d0 + cd8) = lo;
#pragma unroll
      for (int m = 1; m < 8; m <<= 1) {
        s += __shfl_xor(s, m, 64);
        q += __shfl_xor(q, m, 64);
      }
      if (sub == 0)
        colpart[(size_t)dchunk * K_CODES + k0 + rk] = q - 2.0f * EPS * s;
    }
  } else {
    const int xb = bid - 1024;  // 0..255
    if (xb == 0 && t == 0) { loss_acc[0] = 0.0f; counter[0] = 0u; }
    const int wv = t >> 6, lane = t & 63;
#pragma unroll
    for (int i = 0; i < 4; ++i) {
      const int b = xb * 16 + i * 4 + wv;  // one wave per row
      const float* xr = x + (size_t)b * D_DIM;
      float4 v0 = ((const float4*)xr)[lane * 2];
      float4 v1 = ((const float4*)xr)[lane * 2 + 1];
      float vals[8] = {v0.x, v0.y, v0.z, v0.w, v1.x, v1.y, v1.z, v1.w};
      short8 hi, lo;
      float s = 0.f, q = 0.f;
#pragma unroll
      for (int j = 0; j < 8; ++j) {
        float v = vals[j];
        s += v;
        q += v * v;
        unsigned short h = f2bf(v);
        float r = v - bf2f(h);
        hi[j] = (short)h;
        lo[j] = (short)f2bf(r);
      }
      *(short8*)(A + (size_t)b * 1024 + lane * 8) = hi;
      *(short8*)(A + (size_t)b * 1024 + 512 + lane * 8) = lo;
#pragma unroll
      for (int m = 1; m < 64; m <<= 1) {
        s += __shfl_xor(s, m, 64);
        q += __shfl_xor(q, m, 64);
      }
      if (lane == 0) row_term[b] = q + 2.0f * EPS * s + (float)D_DIM * EPS * EPS;
    }
  }
}

// ---------------------------------------------------------------------------
// som_gemm: EXACT R5 structure (proven 212us / 969 TF virtual — above the
// m97-structure plateau). C[b,k] = x[b]·w[:,k] via 3-term hi/lo bf16 MFMA
// (virtual K = 1536), fused packed-min epilogue -> partial[nt][row].
// 128x128 tile, BK=64, 4 waves of 64x64, XOR-swizzled LDS (conflicts = 0),
// __launch_bounds__(256,4) -> 64 VGPR + 64 AGPR = 4 blocks/CU.
// Negative results (do NOT retry):
//  R2: launch_bounds(256,5) -> acc spills, WRITE_SIZE 123MB, 446us.
//  R4: 256x128 tile -> 2 blocks/CU, drain un-hidden, 215us.
//  R6: producer-wave double-buffer -> producer latency-bound, 1 block/CU, 414us.
//  R7: fused finalize w/ __threadfence in all 4096 blocks -> L2-writeback
//      storm, 600us. Cross-block reduction stays in its own tiny kernel.
// ---------------------------------------------------------------------------
__global__ __launch_bounds__(256, 4) void som_gemm_kernel(
    const short* __restrict__ A, const short* __restrict__ W,
    const float* __restrict__ row_term, const float* __restrict__ colpart,
    unsigned long long* __restrict__ partial) {
  __shared__ __align__(16) short As[128 * 64];
  __shared__ __align__(16) short Bs[128 * 64];

  const int nt = blockIdx.x;  // 0..127
  const int mt = blockIdx.y;  // 0..31
  const int m0 = mt * 128, n0 = nt * 128;
  const int tid = threadIdx.x;
  const int wv = tid >> 6, lane = tid & 63;
  const int m_off = (wv & 1) * 64, n_off = (wv >> 1) * 64;
  const int q = lane >> 4, l15 = lane & 15;

  floatx4 acc[4][4];
  const floatx4 zero = {0.f, 0.f, 0.f, 0.f};
#pragma unroll
  for (int mi = 0; mi < 4; ++mi)
#pragma unroll
    for (int ni = 0; ni < 4; ++ni) acc[mi][ni] = zero;

  const int srow = lane >> 3;                      // row within 8-row chunk
  const int scol = ((lane & 7) ^ (srow & 7)) * 8;  // XOR-swizzled source col

  for (int kt = 0; kt < 24; ++kt) {
    // virtual k' in [0,1536): terms hi*hi (kt 0..7), lo*hi (8..15), hi*lo (16..23)
    const int a_k0 = (kt * 64) & 1023;
    const int w_k0 = (kt < 16) ? ((kt * 64) & 511) : (kt * 64 - 512);
    __syncthreads();  // previous iter's ds_reads done before overwrite
#pragma unroll
    for (int i = 0; i < 4; ++i) {
      const int c = wv * 4 + i;  // chunk 0..15, covers rows c*8..c*8+7
      const int row = c * 8 + srow;
      load_lds16(A + (size_t)(m0 + row) * 1024 + a_k0 + scol, As + c * 512);
      load_lds16(W + (size_t)(n0 + row) * 1024 + w_k0 + scol, Bs + c * 512);
    }
    __syncthreads();  // waits vmcnt(0): staging complete
#pragma unroll
    for (int ks = 0; ks < 2; ++ks) {
      const int sw = ((ks * 4 + q) ^ (l15 & 7)) * 8;
      short8 af[4], bf[4];
#pragma unroll
      for (int mi = 0; mi < 4; ++mi)
        af[mi] = *(const short8*)(As + (m_off + mi * 16 + l15) * 64 + sw);
#pragma unroll
      for (int ni = 0; ni < 4; ++ni)
        bf[ni] = *(const short8*)(Bs + (n_off + ni * 16 + l15) * 64 + sw);
#pragma unroll
      for (int mi = 0; mi < 4; ++mi)
#pragma unroll
        for (int ni = 0; ni < 4; ++ni)
          acc[mi][ni] = __builtin_amdgcn_mfma_f32_16x16x32_bf16(
              af[mi], bf[ni], acc[mi][ni], 0, 0, 0);
    }
  }

  // epilogue: ct[k] summed from the 8 d-chunk partials (L2-hot, deterministic)
  float ct[4];
#pragma unroll
  for (int ni = 0; ni < 4; ++ni) {
    const int k = n0 + n_off + ni * 16 + l15;
    float s = 0.f;
#pragma unroll
    for (int c = 0; c < 8; ++c) s += colpart[(size_t)c * K_CODES + k];
    ct[ni] = s;
  }
  float rt[16];
#pragma unroll
  for (int mi = 0; mi < 4; ++mi)
#pragma unroll
    for (int r = 0; r < 4; ++r)
      rt[mi * 4 + r] = row_term[m0 + m_off + mi * 16 + q * 4 + r];

  __syncthreads();  // all waves done reading As before lds_min aliases it
  unsigned long long* lds_min = (unsigned long long*)As;  // [2][128]

#pragma unroll
  for (int mi = 0; mi < 4; ++mi) {
#pragma unroll
    for (int r = 0; r < 4; ++r) {
      unsigned long long v = ~0ull;
#pragma unroll
      for (int ni = 0; ni < 4; ++ni) {
        float d2 = rt[mi * 4 + r] + ct[ni] - 2.0f * acc[mi][ni][r];
        d2 = fmaxf(d2, 0.0f);  // >=0 so float bit order == value order
        unsigned long long p =
            ((unsigned long long)__float_as_uint(d2) << 32) |
            (unsigned int)(n0 + n_off + ni * 16 + l15);
        v = p < v ? p : v;
      }
#pragma unroll
      for (int mms = 1; mms < 16; mms <<= 1) {
        unsigned long long o = __shfl_xor(v, mms, 64);
        v = o < v ? o : v;
      }
      if (l15 == 0) lds_min[(wv >> 1) * 128 + m_off + mi * 16 + q * 4 + r] = v;
    }
  }
  __syncthreads();
  if (tid < 128) {
    unsigned long long v0 = lds_min[tid];
    unsigned long long v1 = lds_min[128 + tid];
    partial[(size_t)nt * B_ROWS + m0 + tid] = v1 < v0 ? v1 : v0;
  }
}

// ---------------------------------------------------------------------------
// finalize: per-row min over 128 N-tiles (4 threads/row x 32 tiles), sqrt,
// gather locations, loss; last-arriving block writes the final mean loss.
// ---------------------------------------------------------------------------
__global__ void finalize_kernel(const unsigned long long* __restrict__ partial,
                                const float* __restrict__ loc,
                                float* __restrict__ out,
                                float* __restrict__ loss_acc,
                                unsigned int* __restrict__ counter) {
  __shared__ unsigned long long red[4][64];
  const int t = threadIdx.x;   // 256
  const int rl = t & 63;       // row-local
  const int p = t >> 6;        // partial-chunk 0..3
  const int b = blockIdx.x * 64 + rl;
  unsigned long long v = ~0ull;
#pragma unroll
  for (int i = 0; i < 32; ++i) {
    int nt = p * 32 + i;
    unsigned long long pv = partial[(size_t)nt * B_ROWS + b];
    v = pv < v ? pv : v;
  }
  red[p][rl] = v;
  __syncthreads();
  if (t < 64) {
    unsigned long long v0 = red[0][t], v1 = red[1][t];
    unsigned long long v2 = red[2][t], v3 = red[3][t];
    v0 = v1 < v0 ? v1 : v0;
    v2 = v3 < v2 ? v3 : v2;
    v0 = v2 < v0 ? v2 : v0;
    unsigned int k = (unsigned int)(v0 & 0xFFFFFFFFu);
    float d2 = __uint_as_float((unsigned int)(v0 >> 32));
    float dist = sqrtf(d2);
    int row = blockIdx.x * 64 + t;
    out[2 * row] = loc[2 * k];
    out[2 * row + 1] = loc[2 * k + 1];
    float s = dist;
#pragma unroll
    for (int m = 1; m < 64; m <<= 1) s += __shfl_xor(s, m, 64);
    if (t == 0) {
      atomicAdd(loss_acc, s);
      __threadfence();
      unsigned int old = atomicAdd(counter, 1u);
      if (old == gridDim.x - 1) {
        __threadfence();
        float total = atomicAdd(loss_acc, 0.0f);  // coherent read-back
        out[2 * B_ROWS] = total * (1.0f / (float)B_ROWS);
      }
    }
  }
}

// ---------------------------------------------------------------------------
// Workspace layout (bytes):
//   A_cat    4096*1024*2  =  8,388,608   @ 0
//   W_cat   16384*1024*2  = 33,554,432   @ 8,388,608
//   row_term  4096*4      =     16,384   @ 41,943,040
//   colpart  8*16384*4    =    524,288   @ 41,959,424
//   partial 128*4096*8    =  4,194,304   @ 42,483,712
//   loss_acc 4                           @ 46,678,016
//   counter  4                           @ 46,678,020
// total ~46.7 MB
// ---------------------------------------------------------------------------
extern "C" void kernel_launch(void* const* d_in, const int* in_sizes, int n_in,
                              void* d_out, int out_size, void* d_ws, size_t ws_size,
                              hipStream_t stream) {
  const float* x = (const float*)d_in[0];
  const float* w = (const float*)d_in[1];
  const float* loc = (const float*)d_in[2];
  float* out = (float*)d_out;
  char* ws = (char*)d_ws;

  short* A = (short*)(ws + 0);
  short* W = (short*)(ws + 8388608);
  float* row_term = (float*)(ws + 41943040);
  float* colpart = (float*)(ws + 41959424);
  unsigned long long* partial = (unsigned long long*)(ws + 42483712);
  float* loss_acc = (float*)(ws + 46678016);
  unsigned int* counter = (unsigned int*)(ws + 46678020);

  prep_kernel<<<1280, 256, 0, stream>>>(x, w, A, W, row_term, colpart,
                                        loss_acc, counter);
  som_gemm_kernel<<<dim3(K_CODES / 128, B_ROWS / 128), 256, 0, stream>>>(
      A, W, row_term, colpart, partial);
  finalize_kernel<<<B_ROWS / 64, 256, 0, stream>>>(partial, loc, out, loss_acc,
                                                   counter);
}